// Round 5
// baseline (127.754 us; speedup 1.0000x reference)
//
#include <hip/hip_runtime.h>

typedef __attribute__((ext_vector_type(8))) short bh8;
typedef __attribute__((ext_vector_type(4))) float f4;
typedef __attribute__((ext_vector_type(4))) unsigned int u32x4;

#define NTHR 512

__device__ __forceinline__ unsigned int f2bf(float f) {
    unsigned int u = __builtin_bit_cast(unsigned int, f);
    u += 0x7FFFu + ((u >> 16) & 1u);
    return u >> 16;
}
__device__ __forceinline__ float bflo(unsigned int d) {
    return __builtin_bit_cast(float, d << 16);
}
__device__ __forceinline__ float bfhi(unsigned int d) {
    return __builtin_bit_cast(float, d & 0xFFFF0000u);
}

// ---------------------------------------------------------------------------
// Kernel 1: x [B][C][H][W] f32 -> xt [B][H][W][C] bf16 (channel-last).
// ---------------------------------------------------------------------------
__global__ __launch_bounds__(256) void transpose_x_kernel(
    const float* __restrict__ x, unsigned short* __restrict__ xt) {
    __shared__ float tile[64 * 65];
    const int bid = blockIdx.x;            // 8*64*4 = 2048
    const int cq = bid & 3;
    const int h  = (bid >> 2) & 63;
    const int b  = bid >> 8;
    const int tid = threadIdx.x;
    const int w = tid & 63, ci = tid >> 6;
    #pragma unroll
    for (int c0 = 0; c0 < 64; c0 += 4)
        tile[(c0 + ci) * 65 + w] =
            x[(((size_t)b * 256 + cq * 64 + c0 + ci) * 64 + h) * 64 + w];
    __syncthreads();
    const int c2 = tid & 63, w2q = tid >> 6;
    #pragma unroll
    for (int w0 = 0; w0 < 64; w0 += 4) {
        int ww = w0 + w2q;
        xt[(((size_t)b * 64 + h) * 64 + ww) * 256 + cq * 64 + c2] =
            (unsigned short)f2bf(tile[c2 * 65 + ww]);
    }
}

// ---------------------------------------------------------------------------
// Kernel 2: pack w_d -> bf16 B-fragments, K reordered k-major (tap-major).
// bp[((cc*9+tt)*16+nb)*64+l][e] = bf16(w_d[nb*16+(l&15)][(cc*32+(l>>4)*8+e)*9+tt])
// ---------------------------------------------------------------------------
__global__ __launch_bounds__(256) void pack_w_kernel(const float* __restrict__ w_d,
                                                     bh8* __restrict__ bp) {
    __shared__ float ldw[16 * 289];
    const int cc = blockIdx.x >> 4;
    const int nb = blockIdx.x & 15;
    const int tid = threadIdx.x;
    for (int i = tid; i < 16 * 288; i += 256) {
        int oi = i / 288, j = i - oi * 288;
        ldw[oi * 289 + j] = w_d[((size_t)(nb * 16 + oi)) * 2304 + cc * 288 + j];
    }
    __syncthreads();
    for (int u = tid; u < 576; u += 256) {
        int tt = u >> 6, l = u & 63;
        int lrow = l & 15, lk = l >> 4;
        bh8 v;
        #pragma unroll
        for (int e = 0; e < 8; ++e)
            v[e] = (short)f2bf(ldw[lrow * 289 + (lk * 8 + e) * 9 + tt]);
        bp[((size_t)(cc * 9 + tt) * 16 + nb) * 64 + l] = v;
    }
}

// ---------------------------------------------------------------------------
// Kernel 3: fused. Block = 32 pixels x 256 outputs, 8 waves, 4 blocks/CU.
// Per group-pair: precompute (p,k) weights+addresses; octet loop is lean.
// XCD swizzle: each XCD owns one batch image (xt slice + bp fit its L2).
// ---------------------------------------------------------------------------
__global__ __launch_bounds__(NTHR, 8) void featadapt_mfma(
    const unsigned short* __restrict__ xt,
    const float* __restrict__ wh_pred,
    const float* __restrict__ w_off,
    const float* __restrict__ b_off,
    const float* __restrict__ b_d,
    const bh8* __restrict__ bp,
    float* __restrict__ out)
{
    extern __shared__ unsigned char lds[];
    unsigned char* samp = lds;                      // 18432 B
    float4* wgt  = (float4*)(lds + 18432);          // 288*16 = 4608
    int4*   adr  = (int4*)(lds + 23040);            // 4608
    int*    sbs  = (int*)(lds + 27648);             // 1152
    float*  whs  = (float*)(lds + 28800);           // 1024
    float*  woff = (float*)(lds + 29824);           // 576
    float*  boff = (float*)(lds + 30400);           // 288  (total 30688)

    const int tid  = threadIdx.x;
    const int orig = blockIdx.x;                    // 1024 blocks
    const int bid  = (orig & 7) * 128 + (orig >> 3);  // XCD -> one batch image
    const int mh = bid & 1;
    const int h  = (bid >> 1) & 63;
    const int b  = bid >> 7;

    if (tid < 256) {
        int j = tid >> 5, p = tid & 31;
        whs[p * 8 + j] = wh_pred[(((size_t)b * 8 + j) * 64 + h) * 64 + mh * 32 + p];
    } else if (tid < 256 + 144) {
        woff[tid - 256] = w_off[tid - 256];
    } else if (tid < 256 + 216) {
        boff[tid - 400] = b_off[tid - 400];
    }

    const int l    = tid & 63;
    const int wv   = tid >> 6;
    const int im   = wv >> 2;
    const int nq   = wv & 3;
    const int lrow = l & 15;
    const int lk   = l >> 4;
    const char* xtb = (const char*)xt + (size_t)b * (64 * 64 * 256 * 2);

    f4 acc[4];
    #pragma unroll
    for (int n = 0; n < 4; ++n) acc[n] = (f4){0.f, 0.f, 0.f, 0.f};

    __syncthreads();

    for (int cc = 0; cc < 8; ++cc) {
        // ---- per-(p,k) precompute when group changes (every 2 chunks) ----
        if ((cc & 1) == 0 && tid < 288) {
            const int g = cc >> 1;
            int p = tid / 9, k = tid - p * 9;
            float wh0 = whs[p * 8 + 2 * g], wh1 = whs[p * 8 + 2 * g + 1];
            int oy = 2 * k, ox = 2 * k + 1;
            float offy = wh0 * woff[(g * 18 + oy) * 2] + wh1 * woff[(g * 18 + oy) * 2 + 1] + boff[g * 18 + oy];
            float offx = wh0 * woff[(g * 18 + ox) * 2] + wh1 * woff[(g * 18 + ox) * 2 + 1] + boff[g * 18 + ox];
            int ky = k / 3;
            float py = offy + (float)(ky - 1 + h);
            float px = offx + (float)(k - ky * 3 - 1 + mh * 32 + p);
            float fy = floorf(py), fx = floorf(px);
            int y0 = (int)fy, x0 = (int)fx;
            float wy = py - fy, wx = px - fx;
            int y0c = min(max(y0, 0), 63), y1c = min(max(y0 + 1, 0), 63);
            int x0c = min(max(x0, 0), 63), x1c = min(max(x0 + 1, 0), 63);
            float my0 = (y0 >= 0 && y0 < 64) ? 1.f : 0.f;
            float my1 = (y0 >= -1 && y0 < 63) ? 1.f : 0.f;
            float mx0 = (x0 >= 0 && x0 < 64) ? 1.f : 0.f;
            float mx1 = (x0 >= -1 && x0 < 63) ? 1.f : 0.f;
            wgt[tid] = make_float4((1.f - wy) * (1.f - wx) * my0 * mx0,
                                   (1.f - wy) * wx * my0 * mx1,
                                   wy * (1.f - wx) * my1 * mx0,
                                   wy * wx * my1 * mx1);
            adr[tid] = make_int4((y0c * 64 + x0c) << 9, (y0c * 64 + x1c) << 9,
                                 (y1c * 64 + x0c) << 9, (y1c * 64 + x1c) << 9);
            sbs[tid] = (p * 576 + k * 64) ^ ((p & 7) << 4);
        }
        __syncthreads();   // pw ready; previous MFMA done reading samp

        // ---- sampling: 1152 octet items ----
        for (int u = tid; u < 1152; u += NTHR) {
            int pk = u >> 2, oct = u & 3;
            float4 w4 = wgt[pk];
            int4   a4 = adr[pk];
            int coff = cc * 64 + oct * 16;
            bh8 t00 = *(const bh8*)(xtb + (a4.x + coff));
            bh8 t01 = *(const bh8*)(xtb + (a4.y + coff));
            bh8 t10 = *(const bh8*)(xtb + (a4.z + coff));
            bh8 t11 = *(const bh8*)(xtb + (a4.w + coff));
            u32x4 q00 = __builtin_bit_cast(u32x4, t00);
            u32x4 q01 = __builtin_bit_cast(u32x4, t01);
            u32x4 q10 = __builtin_bit_cast(u32x4, t10);
            u32x4 q11 = __builtin_bit_cast(u32x4, t11);
            unsigned int ow[4];
            #pragma unroll
            for (int j = 0; j < 4; ++j) {
                float sx = bflo(q00[j]) * w4.x + bflo(q01[j]) * w4.y
                         + bflo(q10[j]) * w4.z + bflo(q11[j]) * w4.w;
                float sy = bfhi(q00[j]) * w4.x + bfhi(q01[j]) * w4.y
                         + bfhi(q10[j]) * w4.z + bfhi(q11[j]) * w4.w;
                ow[j] = f2bf(sx) | (f2bf(sy) << 16);
            }
            int byt = sbs[pk] ^ (oct << 4);
            u32x4 o4 = {ow[0], ow[1], ow[2], ow[3]};
            *(u32x4*)(samp + byt) = o4;
        }
        __syncthreads();

        // ---- MFMA: 9 t-steps ----
        __builtin_amdgcn_s_setprio(1);
        #pragma unroll 3
        for (int tt = 0; tt < 9; ++tt) {
            int row = im * 16 + lrow;
            int byt = (row * 576 + tt * 64 + lk * 16) ^ ((row & 7) << 4);
            bh8 a = *(const bh8*)(samp + byt);
            int tg = cc * 9 + tt;
            #pragma unroll
            for (int n = 0; n < 4; ++n) {
                bh8 bw = bp[((size_t)tg * 16 + nq * 4 + n) * 64 + l];
                acc[n] = __builtin_amdgcn_mfma_f32_16x16x32_bf16(a, bw, acc[n], 0, 0, 0);
            }
        }
        __builtin_amdgcn_s_setprio(0);
    }

    // ---- epilogue ----
    const int wbase = mh * 32 + im * 16 + lk * 4;
    #pragma unroll
    for (int n = 0; n < 4; ++n) {
        int o = (nq * 4 + n) * 16 + lrow;
        float bd = b_d[o];
        f4 v = acc[n];
        float4 s4 = make_float4(v[0] + bd, v[1] + bd, v[2] + bd, v[3] + bd);
        *(float4*)&out[(((size_t)b * 256 + o) * 64 + h) * 64 + wbase] = s4;
    }
}

// ---------------------------------------------------------------------------
extern "C" void kernel_launch(void* const* d_in, const int* in_sizes, int n_in,
                              void* d_out, int out_size, void* d_ws, size_t ws_size,
                              hipStream_t stream) {
    const float* x     = (const float*)d_in[0];
    const float* whp   = (const float*)d_in[1];
    const float* w_off = (const float*)d_in[2];
    const float* b_off = (const float*)d_in[3];
    const float* w_d   = (const float*)d_in[4];
    const float* b_d   = (const float*)d_in[5];
    float* out = (float*)d_out;

    unsigned short* xt = (unsigned short*)d_ws;                    // 16.78 MB
    bh8* bp = (bh8*)((char*)d_ws + (size_t)8 * 64 * 64 * 256 * 2); // +1.18 MB

    hipLaunchKernelGGL(transpose_x_kernel, dim3(2048), dim3(256), 0, stream, x, xt);
    hipLaunchKernelGGL(pack_w_kernel, dim3(128), dim3(256), 0, stream, w_d, bp);
    hipLaunchKernelGGL(featadapt_mfma, dim3(1024), dim3(NTHR), 30688, stream,
                       xt, whp, w_off, b_off, b_d, bp, out);
}

// Round 6
// 114.749 us; speedup vs baseline: 1.1133x; 1.1133x over previous
//
#include <hip/hip_runtime.h>

typedef __attribute__((ext_vector_type(8))) short bh8;
typedef __attribute__((ext_vector_type(16))) float f16v;
typedef __attribute__((ext_vector_type(4))) unsigned int u32x4;

#define NTHR 512

__device__ __forceinline__ unsigned int f2bf(float f) {
    unsigned int u = __builtin_bit_cast(unsigned int, f);
    u += 0x7FFFu + ((u >> 16) & 1u);
    return u >> 16;
}
__device__ __forceinline__ float bflo(unsigned int d) {
    return __builtin_bit_cast(float, d << 16);
}
__device__ __forceinline__ float bfhi(unsigned int d) {
    return __builtin_bit_cast(float, d & 0xFFFF0000u);
}

// ---------------------------------------------------------------------------
// Kernel 1: x [B][C][H][W] f32 -> xt [B][H][W][C] bf16 (channel-last).
// ---------------------------------------------------------------------------
__global__ __launch_bounds__(256) void transpose_x_kernel(
    const float* __restrict__ x, unsigned short* __restrict__ xt) {
    __shared__ float tile[64 * 65];
    const int bid = blockIdx.x;            // 8*64*4 = 2048
    const int cq = bid & 3;
    const int h  = (bid >> 2) & 63;
    const int b  = bid >> 8;
    const int tid = threadIdx.x;
    const int w = tid & 63, ci = tid >> 6;
    #pragma unroll
    for (int c0 = 0; c0 < 64; c0 += 4)
        tile[(c0 + ci) * 65 + w] =
            x[(((size_t)b * 256 + cq * 64 + c0 + ci) * 64 + h) * 64 + w];
    __syncthreads();
    const int c2 = tid & 63, w2q = tid >> 6;
    #pragma unroll
    for (int w0 = 0; w0 < 64; w0 += 4) {
        int ww = w0 + w2q;
        xt[(((size_t)b * 64 + h) * 64 + ww) * 256 + cq * 64 + c2] =
            (unsigned short)f2bf(tile[c2 * 65 + ww]);
    }
}

// ---------------------------------------------------------------------------
// Kernel 2: pack w_d for 32x32x16 MFMA B-fragments, tap-major K.
// bp[((cc*18+tt2)*8+nb)*64+l][e] = bf16(w_d[nb*32+(l&31)]
//                                       [(cc*32+(tt2&1)*16+(l>>5)*8+e)*9 + (tt2>>1)])
// ---------------------------------------------------------------------------
__global__ __launch_bounds__(256) void pack_w32_kernel(const float* __restrict__ w_d,
                                                       bh8* __restrict__ bp) {
    __shared__ float ldw[32 * 289];
    const int cc = blockIdx.x >> 3;         // 8 chunks
    const int nb = blockIdx.x & 7;          // 8 N-frags of 32
    const int tid = threadIdx.x;
    for (int i = tid; i < 32 * 288; i += 256) {
        int oi = i / 288, j = i - oi * 288;
        ldw[oi * 289 + j] = w_d[((size_t)(nb * 32 + oi)) * 2304 + cc * 288 + j];
    }
    __syncthreads();
    for (int u = tid; u < 18 * 64; u += 256) {
        int tt2 = u >> 6, l = u & 63;
        int col = l & 31, hi = l >> 5;
        int tap = tt2 >> 1;
        int cb  = (tt2 & 1) * 16 + hi * 8;
        bh8 v;
        #pragma unroll
        for (int e = 0; e < 8; ++e)
            v[e] = (short)f2bf(ldw[col * 289 + (cb + e) * 9 + tap]);
        bp[((size_t)(cc * 18 + tt2) * 8 + nb) * 64 + l] = v;
    }
}

// ---------------------------------------------------------------------------
// Kernel 3: fused. Block = 32 pixels x 256 outputs, 8 waves.
// Wave wv owns N-columns [wv*32, wv*32+32): each B-frag loaded by ONE wave.
// Double-buffered samp LDS; one barrier per chunk; pw-state in registers.
// ---------------------------------------------------------------------------
__global__ __launch_bounds__(NTHR, 4) void featadapt_mfma(
    const unsigned short* __restrict__ xt,
    const float* __restrict__ wh_pred,
    const float* __restrict__ w_off,
    const float* __restrict__ b_off,
    const float* __restrict__ b_d,
    const bh8* __restrict__ bp,
    float* __restrict__ out)
{
    extern __shared__ unsigned char lds[];
    unsigned char* samp = lds;                      // 2 x 18432
    float* whs  = (float*)(lds + 36864);            // 256 f
    float* woff = (float*)(lds + 37888);            // 144 f
    float* boff = (float*)(lds + 38464);            // 72 f  (total 38752)

    const int tid  = threadIdx.x;
    const int orig = blockIdx.x;                    // 1024 blocks
    const int bid  = (orig & 7) * 128 + (orig >> 3);  // XCD -> one batch image
    const int mh = bid & 1;
    const int h  = (bid >> 1) & 63;
    const int b  = bid >> 7;

    if (tid < 256) {
        int j = tid >> 5, p = tid & 31;
        whs[p * 8 + j] = wh_pred[(((size_t)b * 8 + j) * 64 + h) * 64 + mh * 32 + p];
    } else if (tid < 256 + 144) {
        woff[tid - 256] = w_off[tid - 256];
    } else if (tid < 256 + 216) {
        boff[tid - 400] = b_off[tid - 400];
    }

    const int l  = tid & 63;
    const int wv = tid >> 6;
    const char* xtb = (const char*)xt + (size_t)b * (64 * 64 * 256 * 2);

    // item ownership: id -> (pk = id>>1, octpair = id&1); 576 items total
    const int id0 = tid;
    const int id1 = ((tid & 7) == 0) ? (512 + (tid >> 3)) : -1;
    float4 w40, w41; int4 a40, a41; int sb0 = 0, sb1 = 0;
    const int oh0 = id0 & 1, oh1 = (id1 >= 0) ? (id1 & 1) : 0;

    __syncthreads();   // whs/woff/boff ready

    auto calc = [&](int id, int g, float4& w4, int4& a4, int& sb) {
        int pk = id >> 1;
        int p = pk / 9, k = pk - p * 9;
        float wh0 = whs[p * 8 + 2 * g], wh1 = whs[p * 8 + 2 * g + 1];
        int oy = 2 * k, ox = 2 * k + 1;
        float offy = wh0 * woff[(g * 18 + oy) * 2] + wh1 * woff[(g * 18 + oy) * 2 + 1] + boff[g * 18 + oy];
        float offx = wh0 * woff[(g * 18 + ox) * 2] + wh1 * woff[(g * 18 + ox) * 2 + 1] + boff[g * 18 + ox];
        int ky = k / 3;
        float py = offy + (float)(ky - 1 + h);
        float px = offx + (float)(k - ky * 3 - 1 + mh * 32 + p);
        float fy = floorf(py), fx = floorf(px);
        int y0 = (int)fy, x0 = (int)fx;
        float wy = py - fy, wx = px - fx;
        int y0c = min(max(y0, 0), 63), y1c = min(max(y0 + 1, 0), 63);
        int x0c = min(max(x0, 0), 63), x1c = min(max(x0 + 1, 0), 63);
        float my0 = (y0 >= 0 && y0 < 64) ? 1.f : 0.f;
        float my1 = (y0 >= -1 && y0 < 63) ? 1.f : 0.f;
        float mx0 = (x0 >= 0 && x0 < 64) ? 1.f : 0.f;
        float mx1 = (x0 >= -1 && x0 < 63) ? 1.f : 0.f;
        w4 = make_float4((1.f - wy) * (1.f - wx) * my0 * mx0,
                         (1.f - wy) * wx * my0 * mx1,
                         wy * (1.f - wx) * my1 * mx0,
                         wy * wx * my1 * mx1);
        a4 = make_int4((y0c * 64 + x0c) << 9, (y0c * 64 + x1c) << 9,
                       (y1c * 64 + x0c) << 9, (y1c * 64 + x1c) << 9);
        sb = (p * 576 + k * 64) ^ ((p & 7) << 4);
    };

    auto do_item = [&](unsigned char* buf, int c, float4 w4, int4 a4, int sb, int ohalf) {
        #pragma unroll
        for (int oo = 0; oo < 2; ++oo) {
            int oct = ohalf * 2 + oo;
            int coff = c * 64 + oct * 16;
            bh8 t00 = *(const bh8*)(xtb + (a4.x + coff));
            bh8 t01 = *(const bh8*)(xtb + (a4.y + coff));
            bh8 t10 = *(const bh8*)(xtb + (a4.z + coff));
            bh8 t11 = *(const bh8*)(xtb + (a4.w + coff));
            u32x4 q00 = __builtin_bit_cast(u32x4, t00);
            u32x4 q01 = __builtin_bit_cast(u32x4, t01);
            u32x4 q10 = __builtin_bit_cast(u32x4, t10);
            u32x4 q11 = __builtin_bit_cast(u32x4, t11);
            unsigned int ow[4];
            #pragma unroll
            for (int j = 0; j < 4; ++j) {
                float sx = bflo(q00[j]) * w4.x + bflo(q01[j]) * w4.y
                         + bflo(q10[j]) * w4.z + bflo(q11[j]) * w4.w;
                float sy = bfhi(q00[j]) * w4.x + bfhi(q01[j]) * w4.y
                         + bfhi(q10[j]) * w4.z + bfhi(q11[j]) * w4.w;
                ow[j] = f2bf(sx) | (f2bf(sy) << 16);
            }
            u32x4 o4 = {ow[0], ow[1], ow[2], ow[3]};
            *(u32x4*)(buf + (sb ^ (oct << 4))) = o4;
        }
    };

    f16v acc;
    #pragma unroll
    for (int r = 0; r < 16; ++r) acc[r] = 0.f;

    // prologue: g=0 coords + sample chunk 0 into buf 0
    calc(id0, 0, w40, a40, sb0);
    if (id1 >= 0) calc(id1, 0, w41, a41, sb1);
    do_item(samp, 0, w40, a40, sb0, oh0);
    if (id1 >= 0) do_item(samp, 0, w41, a41, sb1, oh1);

    const int row = l & 31;
    const int hi  = l >> 5;
    const int abase = row * 576 + hi * 16;
    const int aswz  = (row & 7) << 4;

    for (int cc = 0; cc < 8; ++cc) {
        __syncthreads();   // buf[cc&1] sampling complete
        const unsigned char* buf = samp + (cc & 1) * 18432;
        const bh8* bpc = bp + ((size_t)cc * 18 * 8 + wv) * 64 + l;
        __builtin_amdgcn_s_setprio(1);
        #pragma unroll 3
        for (int tt2 = 0; tt2 < 18; ++tt2) {
            bh8 a  = *(const bh8*)(buf + ((abase + tt2 * 32) ^ aswz));
            bh8 bw = bpc[(size_t)tt2 * 512];
            acc = __builtin_amdgcn_mfma_f32_32x32x16_bf16(a, bw, acc, 0, 0, 0);
        }
        __builtin_amdgcn_s_setprio(0);
        if (cc < 7) {
            if (cc & 1) {   // group changes at cc+1 = 2,4,6
                int gn = (cc + 1) >> 1;
                calc(id0, gn, w40, a40, sb0);
                if (id1 >= 0) calc(id1, gn, w41, a41, sb1);
            }
            unsigned char* nbuf = samp + ((cc + 1) & 1) * 18432;
            do_item(nbuf, cc + 1, w40, a40, sb0, oh0);
            if (id1 >= 0) do_item(nbuf, cc + 1, w41, a41, sb1, oh1);
        }
    }

    // epilogue: D col = wv*32 + (l&31); row(pixel) = (r&3) + 8*(r>>2) + 4*hi
    const int o = wv * 32 + (l & 31);
    const float bd = b_d[o];
    const size_t ob = (((size_t)b * 256 + o) * 64 + h) * 64 + mh * 32;
    #pragma unroll
    for (int q = 0; q < 4; ++q) {
        float4 s4 = make_float4(acc[4 * q + 0] + bd, acc[4 * q + 1] + bd,
                                acc[4 * q + 2] + bd, acc[4 * q + 3] + bd);
        *(float4*)&out[ob + hi * 4 + q * 8] = s4;
    }
}

// ---------------------------------------------------------------------------
extern "C" void kernel_launch(void* const* d_in, const int* in_sizes, int n_in,
                              void* d_out, int out_size, void* d_ws, size_t ws_size,
                              hipStream_t stream) {
    const float* x     = (const float*)d_in[0];
    const float* whp   = (const float*)d_in[1];
    const float* w_off = (const float*)d_in[2];
    const float* b_off = (const float*)d_in[3];
    const float* w_d   = (const float*)d_in[4];
    const float* b_d   = (const float*)d_in[5];
    float* out = (float*)d_out;

    unsigned short* xt = (unsigned short*)d_ws;                    // 16.78 MB
    bh8* bp = (bh8*)((char*)d_ws + (size_t)8 * 64 * 64 * 256 * 2); // +1.18 MB

    hipLaunchKernelGGL(transpose_x_kernel, dim3(2048), dim3(256), 0, stream, x, xt);
    hipLaunchKernelGGL(pack_w32_kernel, dim3(64), dim3(256), 0, stream, w_d, bp);
    hipLaunchKernelGGL(featadapt_mfma, dim3(1024), dim3(NTHR), 38752, stream,
                       xt, whp, w_off, b_off, b_d, bp, out);
}

// Round 7
// 100.659 us; speedup vs baseline: 1.2692x; 1.1400x over previous
//
#include <hip/hip_runtime.h>

typedef __attribute__((ext_vector_type(8))) short bh8;
typedef __attribute__((ext_vector_type(16))) float f16v;
typedef __attribute__((ext_vector_type(4))) unsigned int u32x4;

#define NTHR 512

__device__ __forceinline__ unsigned int f2bf(float f) {
    unsigned int u = __builtin_bit_cast(unsigned int, f);
    u += 0x7FFFu + ((u >> 16) & 1u);
    return u >> 16;
}
__device__ __forceinline__ float bflo(unsigned int d) {
    return __builtin_bit_cast(float, d << 16);
}
__device__ __forceinline__ float bfhi(unsigned int d) {
    return __builtin_bit_cast(float, d & 0xFFFF0000u);
}

// ---------------------------------------------------------------------------
// Kernel 1: x [B][C][H][W] f32 -> xt [B][H][W][C] bf16 (channel-last).
// ---------------------------------------------------------------------------
__global__ __launch_bounds__(256) void transpose_x_kernel(
    const float* __restrict__ x, unsigned short* __restrict__ xt) {
    __shared__ float tile[64 * 65];
    const int bid = blockIdx.x;            // 8*64*4 = 2048
    const int cq = bid & 3;
    const int h  = (bid >> 2) & 63;
    const int b  = bid >> 8;
    const int tid = threadIdx.x;
    const int w = tid & 63, ci = tid >> 6;
    #pragma unroll
    for (int c0 = 0; c0 < 64; c0 += 4)
        tile[(c0 + ci) * 65 + w] =
            x[(((size_t)b * 256 + cq * 64 + c0 + ci) * 64 + h) * 64 + w];
    __syncthreads();
    const int c2 = tid & 63, w2q = tid >> 6;
    #pragma unroll
    for (int w0 = 0; w0 < 64; w0 += 4) {
        int ww = w0 + w2q;
        xt[(((size_t)b * 64 + h) * 64 + ww) * 256 + cq * 64 + c2] =
            (unsigned short)f2bf(tile[c2 * 65 + ww]);
    }
}

// ---------------------------------------------------------------------------
// Kernel 2: pack w_d for 32x32x16 MFMA B-fragments, tap-major K.
// bp[((cc*18+tt2)*8+nb)*64+l][e] = bf16(w_d[nb*32+(l&31)]
//                                       [(cc*32+(tt2&1)*16+(l>>5)*8+e)*9 + (tt2>>1)])
// ---------------------------------------------------------------------------
__global__ __launch_bounds__(256) void pack_w32_kernel(const float* __restrict__ w_d,
                                                       bh8* __restrict__ bp) {
    __shared__ float ldw[32 * 289];
    const int cc = blockIdx.x >> 3;
    const int nb = blockIdx.x & 7;
    const int tid = threadIdx.x;
    for (int i = tid; i < 32 * 288; i += 256) {
        int oi = i / 288, j = i - oi * 288;
        ldw[oi * 289 + j] = w_d[((size_t)(nb * 32 + oi)) * 2304 + cc * 288 + j];
    }
    __syncthreads();
    for (int u = tid; u < 18 * 64; u += 256) {
        int tt2 = u >> 6, l = u & 63;
        int col = l & 31, hi = l >> 5;
        int tap = tt2 >> 1;
        int cb  = (tt2 & 1) * 16 + hi * 8;
        bh8 v;
        #pragma unroll
        for (int e = 0; e < 8; ++e)
            v[e] = (short)f2bf(ldw[col * 289 + (cb + e) * 9 + tap]);
        bp[((size_t)(cc * 18 + tt2) * 8 + nb) * 64 + l] = v;
    }
}

// ---------------------------------------------------------------------------
// Kernel 3: fused. Block = (b,h): 64 pixels x 256 outputs, 8 waves.
// Per chunk: coalesced halo-tile stage (T14 issue-early/write-late) ->
// bilinear sampling from LDS tile -> samp frags -> MFMA (2 M-halves/wave).
// ---------------------------------------------------------------------------
__global__ __launch_bounds__(NTHR, 4) void featadapt_mfma(
    const unsigned short* __restrict__ xt,
    const float* __restrict__ wh_pred,
    const float* __restrict__ w_off,
    const float* __restrict__ b_off,
    const float* __restrict__ b_d,
    const bh8* __restrict__ bp,
    float* __restrict__ out)
{
    extern __shared__ unsigned char lds[];
    unsigned char* samp = lds;                       // 64*576 = 36864
    unsigned char* tile = lds + 36864;               // 5*68*64 = 21760
    float* whs  = (float*)(lds + 58624);             // 512 f
    float* woff = (float*)(lds + 60672);             // 144 f
    float* boff = (float*)(lds + 61248);             // 72 f  (total 61536)

    const int tid  = threadIdx.x;
    const int orig = blockIdx.x;                     // 512 blocks
    const int bid  = (orig & 7) * 64 + (orig >> 3);  // XCD -> one batch image
    const int h = bid & 63;
    const int b = bid >> 6;

    {   // stage params
        int j = tid >> 6, p = tid & 63;
        whs[p * 8 + j] = wh_pred[(((size_t)b * 8 + j) * 64 + h) * 64 + p];
    }
    if (tid < 144) woff[tid] = w_off[tid];
    else if (tid < 216) boff[tid - 144] = b_off[tid - 144];

    const char* xtb = (const char*)xt + (size_t)b * (64 * 64 * 512);

    // ---- tile stage slots: 340 cells x 4 octs = 1360 slots of 16B ----
    // LDS dest = slot*16 (linear); source oct pre-swizzled: oct_src = oct ^ (col&3)
    auto slotsrc = [&](int s) -> int {
        int cell = s >> 2, oct = s & 3;
        int row = cell / 68, col = cell - row * 68;
        int gy = min(max(h - 2 + row, 0), 63);
        int gx = min(max(col - 2, 0), 63);
        return (gy * 64 + gx) * 512 + (oct ^ (col & 3)) * 16;
    };
    const int sg0 = slotsrc(tid);
    const int sg1 = slotsrc(tid + 512);
    const int sg2 = slotsrc(tid + 1024);             // used only if tid<336
    const int d0 = tid * 16, d1 = d0 + 8192, d2 = d0 + 16384;

    const int l  = tid & 63;
    const int wv = tid >> 6;
    const int arow = l & 31, hi = l >> 5;
    const int ab0 = arow * 576 + hi * 16;
    const int ab1 = ab0 + 32 * 576;
    const int asw = (arow & 7) << 4;

    f16v acc0, acc1;
    #pragma unroll
    for (int r = 0; r < 16; ++r) { acc0[r] = 0.f; acc1[r] = 0.f; }

    // sampling: wave wv owns pks [wv*72, wv*72+72)  (72 = 8 pixels * 9 taps)
    const int pkA = wv * 72 + l;

    auto sample_pk = [&](int pk, int g) {
        int p = pk / 9, k = pk - p * 9;
        float wh0 = whs[p * 8 + 2 * g], wh1 = whs[p * 8 + 2 * g + 1];
        int oy = 2 * k, ox = oy + 1;
        float offy = wh0 * woff[(g * 18 + oy) * 2] + wh1 * woff[(g * 18 + oy) * 2 + 1] + boff[g * 18 + oy];
        float offx = wh0 * woff[(g * 18 + ox) * 2] + wh1 * woff[(g * 18 + ox) * 2 + 1] + boff[g * 18 + ox];
        int ky = k / 3, kx = k - ky * 3;
        float py = offy + (float)(ky - 1 + h);
        float px = offx + (float)(kx - 1 + p);
        float fy = floorf(py), fx = floorf(px);
        int y0 = (int)fy, x0 = (int)fx;
        float wy = py - fy, wx = px - fx;
        float my0 = (y0 >= 0 && y0 < 64) ? 1.f : 0.f;
        float my1 = (y0 >= -1 && y0 < 63) ? 1.f : 0.f;
        float mx0 = (x0 >= 0 && x0 < 64) ? 1.f : 0.f;
        float mx1 = (x0 >= -1 && x0 < 63) ? 1.f : 0.f;
        float w00 = (1.f - wy) * (1.f - wx) * my0 * mx0;
        float w01 = (1.f - wy) * wx * my0 * mx1;
        float w10 = wy * (1.f - wx) * my1 * mx0;
        float w11 = wy * wx * my1 * mx1;
        int r0 = y0 - (h - 2);                        // 0..3 (|off|<1 guaranteed)
        int c0 = x0 + 2;                              // 0..66
        int A00 = ((r0 * 68 + c0) * 64) | ((c0 & 3) << 4);
        int A01 = ((r0 * 68 + c0 + 1) * 64) | (((c0 + 1) & 3) << 4);
        int A10 = A00 + 68 * 64;
        int A11 = A01 + 68 * 64;
        int sbyt = (p * 576 + k * 64) ^ ((p & 7) << 4);
        #pragma unroll
        for (int oct = 0; oct < 4; ++oct) {
            int ox4 = oct << 4;
            u32x4 q00 = *(const u32x4*)(tile + (A00 ^ ox4));
            u32x4 q01 = *(const u32x4*)(tile + (A01 ^ ox4));
            u32x4 q10 = *(const u32x4*)(tile + (A10 ^ ox4));
            u32x4 q11 = *(const u32x4*)(tile + (A11 ^ ox4));
            unsigned int ow[4];
            #pragma unroll
            for (int j = 0; j < 4; ++j) {
                float sx = bflo(q00[j]) * w00 + bflo(q01[j]) * w01
                         + bflo(q10[j]) * w10 + bflo(q11[j]) * w11;
                float sy = bfhi(q00[j]) * w00 + bfhi(q01[j]) * w01
                         + bfhi(q10[j]) * w10 + bfhi(q11[j]) * w11;
                ow[j] = f2bf(sx) | (f2bf(sy) << 16);
            }
            u32x4 o4 = {ow[0], ow[1], ow[2], ow[3]};
            *(u32x4*)(samp + (sbyt ^ ox4)) = o4;
        }
    };

    // ---- prologue: stage tile chunk 0 ----
    {
        u32x4 g0 = *(const u32x4*)(xtb + sg0);
        u32x4 g1 = *(const u32x4*)(xtb + sg1);
        *(u32x4*)(tile + d0) = g0;
        *(u32x4*)(tile + d1) = g1;
        if (tid < 336) {
            u32x4 g2 = *(const u32x4*)(xtb + sg2);
            *(u32x4*)(tile + d2) = g2;
        }
    }
    __syncthreads();   // params + tile(0) ready

    for (int cc = 0; cc < 8; ++cc) {
        const int g = cc >> 1;
        // ---- sampling phase: read tile, write samp ----
        sample_pk(pkA, g);
        if (l < 8) sample_pk(wv * 72 + 64 + l, g);
        __syncthreads();   // samp ready; tile free

        // ---- issue next tile's loads (land during MFMA) ----
        u32x4 g0, g1, g2;
        const int nxt = (cc + 1) * 64;
        if (cc < 7) {
            g0 = *(const u32x4*)(xtb + sg0 + nxt);
            g1 = *(const u32x4*)(xtb + sg1 + nxt);
            if (tid < 336) g2 = *(const u32x4*)(xtb + sg2 + nxt);
        }

        // ---- MFMA: 18 t-steps, 2 M-halves ----
        const bh8* bpc = bp + ((size_t)cc * 18 * 8 + wv) * 64 + l;
        __builtin_amdgcn_s_setprio(1);
        #pragma unroll 6
        for (int tt2 = 0; tt2 < 18; ++tt2) {
            bh8 a0 = *(const bh8*)(samp + ((ab0 + tt2 * 32) ^ asw));
            bh8 a1 = *(const bh8*)(samp + ((ab1 + tt2 * 32) ^ asw));
            bh8 bw = bpc[(size_t)tt2 * 512];
            acc0 = __builtin_amdgcn_mfma_f32_32x32x16_bf16(a0, bw, acc0, 0, 0, 0);
            acc1 = __builtin_amdgcn_mfma_f32_32x32x16_bf16(a1, bw, acc1, 0, 0, 0);
        }
        __builtin_amdgcn_s_setprio(0);

        // ---- write next tile ----
        if (cc < 7) {
            *(u32x4*)(tile + d0) = g0;
            *(u32x4*)(tile + d1) = g1;
            if (tid < 336) *(u32x4*)(tile + d2) = g2;
        }
        __syncthreads();   // tile(cc+1) ready; MFMA done -> samp free
    }

    // ---- epilogue ----
    const int o = wv * 32 + arow;
    const float bd = b_d[o];
    const size_t ob = (((size_t)b * 256 + o) * 64 + h) * 64;
    #pragma unroll
    for (int q = 0; q < 4; ++q) {
        float4 s0 = make_float4(acc0[4 * q + 0] + bd, acc0[4 * q + 1] + bd,
                                acc0[4 * q + 2] + bd, acc0[4 * q + 3] + bd);
        *(float4*)&out[ob + hi * 4 + q * 8] = s0;
        float4 s1 = make_float4(acc1[4 * q + 0] + bd, acc1[4 * q + 1] + bd,
                                acc1[4 * q + 2] + bd, acc1[4 * q + 3] + bd);
        *(float4*)&out[ob + 32 + hi * 4 + q * 8] = s1;
    }
}

// ---------------------------------------------------------------------------
extern "C" void kernel_launch(void* const* d_in, const int* in_sizes, int n_in,
                              void* d_out, int out_size, void* d_ws, size_t ws_size,
                              hipStream_t stream) {
    const float* x     = (const float*)d_in[0];
    const float* whp   = (const float*)d_in[1];
    const float* w_off = (const float*)d_in[2];
    const float* b_off = (const float*)d_in[3];
    const float* w_d   = (const float*)d_in[4];
    const float* b_d   = (const float*)d_in[5];
    float* out = (float*)d_out;

    unsigned short* xt = (unsigned short*)d_ws;                    // 16.78 MB
    bh8* bp = (bh8*)((char*)d_ws + (size_t)8 * 64 * 64 * 256 * 2); // +1.18 MB

    hipLaunchKernelGGL(transpose_x_kernel, dim3(2048), dim3(256), 0, stream, x, xt);
    hipLaunchKernelGGL(pack_w32_kernel, dim3(64), dim3(256), 0, stream, w_d, bp);
    hipLaunchKernelGGL(featadapt_mfma, dim3(512), dim3(NTHR), 61536, stream,
                       xt, whp, w_off, b_off, b_d, bp, out);
}

// Round 8
// 91.819 us; speedup vs baseline: 1.3914x; 1.0963x over previous
//
#include <hip/hip_runtime.h>

typedef __attribute__((ext_vector_type(8))) short bh8;
typedef __attribute__((ext_vector_type(16))) float f16v;
typedef __attribute__((ext_vector_type(4))) unsigned int u32x4;

#define NTHR 512

__device__ __forceinline__ unsigned int f2bf(float f) {
    unsigned int u = __builtin_bit_cast(unsigned int, f);
    u += 0x7FFFu + ((u >> 16) & 1u);
    return u >> 16;
}
__device__ __forceinline__ float bflo(unsigned int d) {
    return __builtin_bit_cast(float, d << 16);
}
__device__ __forceinline__ float bfhi(unsigned int d) {
    return __builtin_bit_cast(float, d & 0xFFFF0000u);
}

// ---------------------------------------------------------------------------
// Kernel 1: x [B][C][H][W] f32 -> xt [B][H][W][C] bf16 (channel-last).
// ---------------------------------------------------------------------------
__global__ __launch_bounds__(256) void transpose_x_kernel(
    const float* __restrict__ x, unsigned short* __restrict__ xt) {
    __shared__ float tile[64 * 65];
    const int bid = blockIdx.x;            // 8*64*4 = 2048
    const int cq = bid & 3;
    const int h  = (bid >> 2) & 63;
    const int b  = bid >> 8;
    const int tid = threadIdx.x;
    const int w = tid & 63, ci = tid >> 6;
    #pragma unroll
    for (int c0 = 0; c0 < 64; c0 += 4)
        tile[(c0 + ci) * 65 + w] =
            x[(((size_t)b * 256 + cq * 64 + c0 + ci) * 64 + h) * 64 + w];
    __syncthreads();
    const int c2 = tid & 63, w2q = tid >> 6;
    #pragma unroll
    for (int w0 = 0; w0 < 64; w0 += 4) {
        int ww = w0 + w2q;
        xt[(((size_t)b * 64 + h) * 64 + ww) * 256 + cq * 64 + c2] =
            (unsigned short)f2bf(tile[c2 * 65 + ww]);
    }
}

// ---------------------------------------------------------------------------
// Kernel 2: pack w_d for 32x32x16 MFMA B-fragments, tap-major K.
// ---------------------------------------------------------------------------
__global__ __launch_bounds__(256) void pack_w32_kernel(const float* __restrict__ w_d,
                                                       bh8* __restrict__ bp) {
    __shared__ float ldw[32 * 289];
    const int cc = blockIdx.x >> 3;
    const int nb = blockIdx.x & 7;
    const int tid = threadIdx.x;
    for (int i = tid; i < 32 * 288; i += 256) {
        int oi = i / 288, j = i - oi * 288;
        ldw[oi * 289 + j] = w_d[((size_t)(nb * 32 + oi)) * 2304 + cc * 288 + j];
    }
    __syncthreads();
    for (int u = tid; u < 18 * 64; u += 256) {
        int tt2 = u >> 6, l = u & 63;
        int col = l & 31, hi = l >> 5;
        int tap = tt2 >> 1;
        int cb  = (tt2 & 1) * 16 + hi * 8;
        bh8 v;
        #pragma unroll
        for (int e = 0; e < 8; ++e)
            v[e] = (short)f2bf(ldw[col * 289 + (cb + e) * 9 + tap]);
        bp[((size_t)(cc * 18 + tt2) * 8 + nb) * 64 + l] = v;
    }
}

// ---------------------------------------------------------------------------
// Kernel 3: fused. Block = (b,h): 64 pixels x 256 outputs, 8 waves.
// R8: column-swizzled tile (conflict-free tap reads), k-swizzled samp writes,
// per-group cached coords, truncation pack.
// ---------------------------------------------------------------------------
struct PK { float w00, w01, w10, w11; int A00, A01, sb; };

__global__ __launch_bounds__(NTHR, 4) void featadapt_mfma(
    const unsigned short* __restrict__ xt,
    const float* __restrict__ wh_pred,
    const float* __restrict__ w_off,
    const float* __restrict__ b_off,
    const float* __restrict__ b_d,
    const bh8* __restrict__ bp,
    float* __restrict__ out)
{
    extern __shared__ unsigned char lds[];
    unsigned char* samp = lds;                       // 64*576 = 36864
    unsigned char* tile = lds + 36864;               // 5*68*64 = 21760
    float* whs  = (float*)(lds + 58624);             // 512 f
    float* woff = (float*)(lds + 60672);             // 144 f
    float* boff = (float*)(lds + 61248);             // 72 f  (total 61536)

    const int tid  = threadIdx.x;
    const int orig = blockIdx.x;                     // 512 blocks
    const int bid  = (orig & 7) * 64 + (orig >> 3);  // XCD -> one batch image
    const int h = bid & 63;
    const int b = bid >> 6;

    {   // stage params
        int j = tid >> 6, p = tid & 63;
        whs[p * 8 + j] = wh_pred[(((size_t)b * 8 + j) * 64 + h) * 64 + p];
    }
    if (tid < 144) woff[tid] = w_off[tid];
    else if (tid < 216) boff[tid - 144] = b_off[tid - 144];

    const char* xtb = (const char*)xt + (size_t)b * (64 * 64 * 512);

    // ---- tile stage slots: 340 cells x 4 octs; col-swizzled source oct ----
    auto slotsrc = [&](int s) -> int {
        int cell = s >> 2, oct = s & 3;
        int row = cell / 68, col = cell - row * 68;
        int gy = min(max(h - 2 + row, 0), 63);
        int gx = min(max(col - 2, 0), 63);
        int osrc = oct ^ ((col + (col >> 2)) & 3);
        return (gy * 64 + gx) * 512 + osrc * 16;
    };
    const int sg0 = slotsrc(tid);
    const int sg1 = slotsrc(tid + 512);
    const int sg2 = slotsrc(tid + 1024);             // used only if tid<336
    const int d0 = tid * 16, d1 = d0 + 8192, d2 = d0 + 16384;

    const int l  = tid & 63;
    const int wv = tid >> 6;
    const int arow = l & 31, hi = l >> 5;
    const int ab0 = arow * 576 + hi * 16;
    const int ab1 = ab0 + 32 * 576;
    const int asw = (arow & 7) << 4;

    f16v acc0, acc1;
    #pragma unroll
    for (int r = 0; r < 16; ++r) { acc0[r] = 0.f; acc1[r] = 0.f; }

    // sampling: wave wv owns pks [wv*72, wv*72+72)
    const int pkA = wv * 72 + l;
    const int pkB = wv * 72 + 64 + l;                // only lanes l<8

    auto calcpk = [&](int pk, int g, PK& S) {
        int p = pk / 9, k = pk - p * 9;
        float wh0 = whs[p * 8 + 2 * g], wh1 = whs[p * 8 + 2 * g + 1];
        int oy = 2 * k, ox = oy + 1;
        float offy = wh0 * woff[(g * 18 + oy) * 2] + wh1 * woff[(g * 18 + oy) * 2 + 1] + boff[g * 18 + oy];
        float offx = wh0 * woff[(g * 18 + ox) * 2] + wh1 * woff[(g * 18 + ox) * 2 + 1] + boff[g * 18 + ox];
        int ky = k / 3, kx = k - ky * 3;
        float py = offy + (float)(ky - 1 + h);
        float px = offx + (float)(kx - 1 + p);
        float fy = floorf(py), fx = floorf(px);
        int y0 = (int)fy, x0 = (int)fx;
        float wy = py - fy, wx = px - fx;
        float my0 = (y0 >= 0 && y0 < 64) ? 1.f : 0.f;
        float my1 = (y0 >= -1 && y0 < 63) ? 1.f : 0.f;
        float mx0 = (x0 >= 0 && x0 < 64) ? 1.f : 0.f;
        float mx1 = (x0 >= -1 && x0 < 63) ? 1.f : 0.f;
        S.w00 = (1.f - wy) * (1.f - wx) * my0 * mx0;
        S.w01 = (1.f - wy) * wx * my0 * mx1;
        S.w10 = wy * (1.f - wx) * my1 * mx0;
        S.w11 = wy * wx * my1 * mx1;
        int r0 = y0 - (h - 2);                       // 0..3 (|off|<1)
        int c0 = x0 + 2, c1 = c0 + 1;                // 0..67
        S.A00 = (r0 * 68 + c0) * 64 + (((c0 + (c0 >> 2)) & 3) << 4);
        S.A01 = (r0 * 68 + c1) * 64 + (((c1 + (c1 >> 2)) & 3) << 4);
        S.sb  = (p * 576 + k * 64) ^ ((p & 7) << 4) ^ (((k >> 1) & 3) << 4);
    };

    auto sample_pk = [&](const PK& S) {
        #pragma unroll
        for (int oct = 0; oct < 4; ++oct) {
            int ox4 = oct << 4;
            u32x4 q00 = *(const u32x4*)(tile + (S.A00 ^ ox4));
            u32x4 q01 = *(const u32x4*)(tile + (S.A01 ^ ox4));
            u32x4 q10 = *(const u32x4*)(tile + ((S.A00 + 68 * 64) ^ ox4));
            u32x4 q11 = *(const u32x4*)(tile + ((S.A01 + 68 * 64) ^ ox4));
            unsigned int ow[4];
            #pragma unroll
            for (int j = 0; j < 4; ++j) {
                float sx = bflo(q00[j]) * S.w00 + bflo(q01[j]) * S.w01
                         + bflo(q10[j]) * S.w10 + bflo(q11[j]) * S.w11;
                float sy = bfhi(q00[j]) * S.w00 + bfhi(q01[j]) * S.w01
                         + bfhi(q10[j]) * S.w10 + bfhi(q11[j]) * S.w11;
                ow[j] = (__builtin_bit_cast(unsigned int, sx) >> 16)
                      | (__builtin_bit_cast(unsigned int, sy) & 0xFFFF0000u);
            }
            u32x4 o4 = {ow[0], ow[1], ow[2], ow[3]};
            *(u32x4*)(samp + (S.sb ^ ox4)) = o4;
        }
    };

    // ---- prologue: stage tile chunk 0 ----
    {
        u32x4 g0 = *(const u32x4*)(xtb + sg0);
        u32x4 g1 = *(const u32x4*)(xtb + sg1);
        *(u32x4*)(tile + d0) = g0;
        *(u32x4*)(tile + d1) = g1;
        if (tid < 336) {
            u32x4 g2 = *(const u32x4*)(xtb + sg2);
            *(u32x4*)(tile + d2) = g2;
        }
    }
    __syncthreads();   // params + tile(0) ready

    PK s0, s1;
    for (int g = 0; g < 4; ++g) {
        calcpk(pkA, g, s0);
        if (l < 8) calcpk(pkB, g, s1);
        #pragma unroll
        for (int sub = 0; sub < 2; ++sub) {
            const int cc = g * 2 + sub;
            // ---- sampling phase: read tile, write samp ----
            sample_pk(s0);
            if (l < 8) sample_pk(s1);
            __syncthreads();   // samp ready; tile free

            // ---- issue next tile's loads (land during MFMA) ----
            u32x4 g0v, g1v, g2v;
            const int nxt = (cc + 1) * 64;
            if (cc < 7) {
                g0v = *(const u32x4*)(xtb + sg0 + nxt);
                g1v = *(const u32x4*)(xtb + sg1 + nxt);
                if (tid < 336) g2v = *(const u32x4*)(xtb + sg2 + nxt);
            }

            // ---- MFMA: 18 t-steps, 2 M-halves ----
            const bh8* bpc = bp + ((size_t)cc * 18 * 8 + wv) * 64 + l;
            __builtin_amdgcn_s_setprio(1);
            #pragma unroll 6
            for (int tt2 = 0; tt2 < 18; ++tt2) {
                const int kx4 = ((tt2 >> 2) & 3) << 4;
                bh8 a0 = *(const bh8*)(samp + (((ab0 + tt2 * 32) ^ asw) ^ kx4));
                bh8 a1 = *(const bh8*)(samp + (((ab1 + tt2 * 32) ^ asw) ^ kx4));
                bh8 bw = bpc[(size_t)tt2 * 512];
                acc0 = __builtin_amdgcn_mfma_f32_32x32x16_bf16(a0, bw, acc0, 0, 0, 0);
                acc1 = __builtin_amdgcn_mfma_f32_32x32x16_bf16(a1, bw, acc1, 0, 0, 0);
            }
            __builtin_amdgcn_s_setprio(0);

            // ---- write next tile ----
            if (cc < 7) {
                *(u32x4*)(tile + d0) = g0v;
                *(u32x4*)(tile + d1) = g1v;
                if (tid < 336) *(u32x4*)(tile + d2) = g2v;
            }
            __syncthreads();   // tile(cc+1) ready; MFMA done -> samp free
        }
    }

    // ---- epilogue ----
    const int o = wv * 32 + arow;
    const float bd = b_d[o];
    const size_t ob = (((size_t)b * 256 + o) * 64 + h) * 64;
    #pragma unroll
    for (int q = 0; q < 4; ++q) {
        float4 s4a = make_float4(acc0[4 * q + 0] + bd, acc0[4 * q + 1] + bd,
                                 acc0[4 * q + 2] + bd, acc0[4 * q + 3] + bd);
        *(float4*)&out[ob + hi * 4 + q * 8] = s4a;
        float4 s4b = make_float4(acc1[4 * q + 0] + bd, acc1[4 * q + 1] + bd,
                                 acc1[4 * q + 2] + bd, acc1[4 * q + 3] + bd);
        *(float4*)&out[ob + 32 + hi * 4 + q * 8] = s4b;
    }
}

// ---------------------------------------------------------------------------
extern "C" void kernel_launch(void* const* d_in, const int* in_sizes, int n_in,
                              void* d_out, int out_size, void* d_ws, size_t ws_size,
                              hipStream_t stream) {
    const float* x     = (const float*)d_in[0];
    const float* whp   = (const float*)d_in[1];
    const float* w_off = (const float*)d_in[2];
    const float* b_off = (const float*)d_in[3];
    const float* w_d   = (const float*)d_in[4];
    const float* b_d   = (const float*)d_in[5];
    float* out = (float*)d_out;

    unsigned short* xt = (unsigned short*)d_ws;                    // 16.78 MB
    bh8* bp = (bh8*)((char*)d_ws + (size_t)8 * 64 * 64 * 256 * 2); // +1.18 MB

    hipLaunchKernelGGL(transpose_x_kernel, dim3(2048), dim3(256), 0, stream, x, xt);
    hipLaunchKernelGGL(pack_w32_kernel, dim3(64), dim3(256), 0, stream, w_d, bp);
    hipLaunchKernelGGL(featadapt_mfma, dim3(512), dim3(NTHR), 61536, stream,
                       xt, whp, w_off, b_off, b_d, bp, out);
}